// Round 4
// baseline (527.908 us; speedup 1.0000x reference)
//
#include <hip/hip_runtime.h>

#define TT 2048

// r = 1/(1+exp2(z)); tanh(y) = 1 - 2r with z = 2*log2(e)*y folded into weights
__device__ __forceinline__ float sigr(float z) {
    float t = __builtin_amdgcn_exp2f(z);
    return __builtin_amdgcn_rcpf(1.0f + t);
}

__global__ __launch_bounds__(64, 1)
void stn_lane_kernel(const float* __restrict__ x,
                     const float* __restrict__ W1,
                     const float* __restrict__ W2,
                     const float* __restrict__ b2,
                     const float* __restrict__ W3,
                     const float* __restrict__ W4,
                     float* __restrict__ out, int B)
{
    const int b = blockIdx.x * blockDim.x + threadIdx.x;
    if (b >= B) return;
    const float K = 2.8853900817779268f; // 2*log2(e)

    // Wave-uniform weights -> SGPRs. Folded form: every layer consumes
    // r (=1/(1+2^z)) directly: A' = -2K*W, B' = K*(bias + sum_j W_j).
    float Kx[4], Ks[4], B2[4], B3[4], A2[4][4], A3[4][4], A4[4];
    float C4 = 0.f;
    #pragma unroll
    for (int i = 0; i < 4; ++i) {
        Kx[i] = W1[2*i]   * K;
        Ks[i] = W1[2*i+1] * K;
        float s2 = b2[i], s3 = 0.f;
        #pragma unroll
        for (int j = 0; j < 4; ++j) {
            A2[i][j] = -2.f * K * W2[i*4+j];
            A3[i][j] = -2.f * K * W3[i*4+j];
            s2 += W2[i*4+j];
            s3 += W3[i*4+j];
        }
        B2[i] = s2 * K;
        B3[i] = s3 * K;
        A4[i] = -2.f * W4[i];
        C4 += W4[i];
    }

    const float* xp = x + b;
    float* op = out + b;

    float cur[8], nxt[8];
    #pragma unroll
    for (int j = 0; j < 8; ++j) cur[j] = __builtin_nontemporal_load(xp + j*B);
    #pragma unroll
    for (int j = 0; j < 8; ++j) nxt[j] = __builtin_nontemporal_load(xp + (8+j)*B);

    // State: psum = sum_j A4_j*r3_j of previous step (0 initially);
    // sC = s_t + C4 (s_{-1}+C4 := 0); pre_i = Kx_i*x_t + Ks_i*(s_{t-1}+C4)
    // so z1_i(t) = pre_i + Ks_i*psum.
    float psum = 0.f, sC = C4;
    float pre[4];
    #pragma unroll
    for (int i = 0; i < 4; ++i) pre[i] = Kx[i] * cur[0];

    for (int t = 0; t < TT; t += 8) {
        #pragma unroll
        for (int k = 0; k < 8; ++k) {
            // ---- layer 1 (chain head): 4 parallel unit-chains ----
            float r1[4];
            #pragma unroll
            for (int i = 0; i < 4; ++i)
                r1[i] = sigr(fmaf(Ks[i], psum, pre[i]));
            // off-chain: pre for next step (uses old sC = s_t + C4)
            float xn = (k < 7) ? cur[k+1] : nxt[0];
            #pragma unroll
            for (int i = 0; i < 4; ++i)
                pre[i] = fmaf(Ks[i], sC, Kx[i] * xn);
            // ---- layer 2: depth-3 fma trees, 4-way ILP ----
            float r2[4];
            #pragma unroll
            for (int i = 0; i < 4; ++i) {
                float f = fmaf(A2[i][1], r1[1], fmaf(A2[i][0], r1[0], B2[i]));
                float g = fmaf(A2[i][3], r1[3], A2[i][2] * r1[2]);
                r2[i] = sigr(f + g);
            }
            // ---- layer 3 ----
            float r3[4];
            #pragma unroll
            for (int i = 0; i < 4; ++i) {
                float f = fmaf(A3[i][1], r2[1], fmaf(A3[i][0], r2[0], B3[i]));
                float g = fmaf(A3[i][3], r2[3], A3[i][2] * r2[2]);
                r3[i] = sigr(f + g);
            }
            // ---- layer 4: depth-3 tree -> psum ----
            float f4 = fmaf(A4[1], r3[1], A4[0] * r3[0]);
            float g4 = fmaf(A4[3], r3[3], A4[2] * r3[2]);
            psum = f4 + g4;
            // off-chain: output + state carry
            float o = sC + psum;        // = s_{t+1}
            __builtin_nontemporal_store(o, op);
            op += B;
            sC = o + C4;
        }
        // rotate x buffers, prefetch block t+16
        #pragma unroll
        for (int j = 0; j < 8; ++j) cur[j] = nxt[j];
        if (t + 16 < TT) {
            #pragma unroll
            for (int j = 0; j < 8; ++j)
                nxt[j] = __builtin_nontemporal_load(xp + (size_t)(t+16+j)*B);
        }
    }
}

extern "C" void kernel_launch(void* const* d_in, const int* in_sizes, int n_in,
                              void* d_out, int out_size, void* d_ws, size_t ws_size,
                              hipStream_t stream)
{
    const float* x  = (const float*)d_in[0];
    const float* W1 = (const float*)d_in[1];
    const float* A2 = (const float*)d_in[2];
    const float* A3 = (const float*)d_in[3];
    const float* W3 = (const float*)d_in[4];
    const float* W4 = (const float*)d_in[5];
    const float* W2 = (in_sizes[2] == 16) ? A2 : A3;
    const float* b2 = (in_sizes[2] == 16) ? A3 : A2;

    const int B = in_sizes[0] / TT;
    float* out = (float*)d_out;

    dim3 block(64);
    dim3 grid((B + 63) / 64);   // 256 blocks -> 1 wave per CU, private SIMD
    hipLaunchKernelGGL(stn_lane_kernel, grid, block, 0, stream,
                       x, W1, W2, b2, W3, W4, out, B);
}

// Round 5
// 499.920 us; speedup vs baseline: 1.0560x; 1.0560x over previous
//
#include <hip/hip_runtime.h>

#define TT 2048

// DPP quad_perm cross-lane move (VALU pipe)
template<int CTRL>
__device__ __forceinline__ float dpp_f(float x) {
    return __int_as_float(__builtin_amdgcn_mov_dpp(__float_as_int(x), CTRL, 0xf, 0xf, true));
}
#define QP_ROT1 0x39  // lane i <- lane (i+1)&3
#define QP_ROT2 0x4E  // lane i <- lane (i+2)&3
#define QP_ROT3 0x93  // lane i <- lane (i+3)&3

// r = 1/(1+exp2(z)) with the divide done by bit-trick seed + 3 Newton steps
// (VALU-only, ~4e-11 rel err — replaces the long-latency v_rcp on the chain).
// CLAMP=true guards u=inf (only layer 1 can overflow: |s| can be large).
template<bool CLAMP>
__device__ __forceinline__ float sigr_nr(float z) {
    float t = __builtin_amdgcn_exp2f(z);
    float u = 1.0f + t;
    if (CLAMP) u = fminf(u, 1e30f);      // inf would poison the bit-trick seed
    float r = __int_as_float(0x7EF311C3u - __float_as_uint(u));
    r = r * fmaf(-u, r, 2.0f);
    r = r * fmaf(-u, r, 2.0f);
    r = r * fmaf(-u, r, 2.0f);
    return r;
}

__global__ __launch_bounds__(512, 2)
void stn_nr_kernel(const float* __restrict__ x,
                   const float* __restrict__ W1,
                   const float* __restrict__ W2,
                   const float* __restrict__ b2,
                   const float* __restrict__ W3,
                   const float* __restrict__ W4,
                   float* __restrict__ out, int B)
{
    const int tid = blockIdx.x * blockDim.x + threadIdx.x;
    const int o   = tid & 7;   // octet lane; o = store row in the 8-step batch
    const int q   = o & 3;     // hidden-unit index
    const int b   = tid >> 3;  // sequence index
    if (b >= B) return;
    const float K = 2.8853900817779268f; // 2*log2(e)

    // Folded weights (consume r directly): A' = -2K*W, B' = K*(bias + sum_j W_j)
    const float Kw1x = W1[2*q]   * K;
    const float Kw1s = W1[2*q+1] * K;
    float B2 = b2[q], B3 = 0.f, C4 = 0.f;
    float a2[4], a3[4], a4[4], Kf[4];
    #pragma unroll
    for (int r = 0; r < 4; ++r) {
        const int j = (q + r) & 3;           // rotation-aligned gather
        a2[r] = -2.f * K * W2[q*4 + j];
        a3[r] = -2.f * K * W3[q*4 + j];
        a4[r] = -2.f * W4[j];
        B2 += W2[q*4 + r];
        B3 += W3[q*4 + r];
        C4 += W4[r];
    }
    B2 *= K; B3 *= K;
    #pragma unroll
    for (int r = 0; r < 4; ++r) Kf[r] = Kw1s * a4[r];  // layer4->layer1 fused coeffs

    const float* xp = x + b;
    float* op = out + b + (size_t)o * B;

    float cur[8], nxt[8];
    #pragma unroll
    for (int j = 0; j < 8; ++j) cur[j] = __builtin_nontemporal_load(xp + j*B);
    #pragma unroll
    for (int j = 0; j < 8; ++j) nxt[j] = __builtin_nontemporal_load(xp + (8+j)*B);

    // Carried state: z1 (next step's layer-1 preactivation), sC = s_t + C4.
    // s_0 = 0: z1(0) = Kw1x*x_0.
    float z1 = Kw1x * cur[0];
    float sC = C4;

    for (int t = 0; t < TT; t += 8) {
        float outv[8];
        #pragma unroll
        for (int k = 0; k < 8; ++k) {
            // ---- layer 1 (chain head) ----
            float r1 = sigr_nr<true>(z1);
            // off-chain: pre2 for next step (uses current sC = s_t + C4)
            float xn = (k < 7) ? cur[k+1] : nxt[0];
            float pre2 = fmaf(Kw1s, sC, Kw1x * xn);
            // ---- layer 2 ----
            float rA = dpp_f<QP_ROT1>(r1);
            float rB = dpp_f<QP_ROT2>(r1);
            float rC = dpp_f<QP_ROT3>(r1);
            float m0 = fmaf(a2[0], r1, B2);
            float u1 = fmaf(a2[1], rA, m0);
            float v  = a2[2] * rB;
            float u2 = fmaf(a2[3], rC, v);
            float r2 = sigr_nr<false>(u1 + u2);
            // ---- layer 3 ----
            rA = dpp_f<QP_ROT1>(r2);
            rB = dpp_f<QP_ROT2>(r2);
            rC = dpp_f<QP_ROT3>(r2);
            m0 = fmaf(a3[0], r2, B3);
            u1 = fmaf(a3[1], rA, m0);
            v  = a3[2] * rB;
            u2 = fmaf(a3[3], rC, v);
            float r3 = sigr_nr<false>(u1 + u2);
            // ---- layer 4 fused into next z1 (chain tail, serial fma) ----
            float rA3 = dpp_f<QP_ROT1>(r3);
            float rB3 = dpp_f<QP_ROT2>(r3);
            float rC3 = dpp_f<QP_ROT3>(r3);
            z1 = fmaf(Kf[0], r3, pre2);
            z1 = fmaf(Kf[1], rA3, z1);
            z1 = fmaf(Kf[2], rB3, z1);
            z1 = fmaf(Kf[3], rC3, z1);
            // off-chain: psum tree for the output/state
            float p0 = a4[0] * r3;
            float t1 = fmaf(a4[1], rA3, p0);
            float t2 = fmaf(a4[3], rC3, a4[2] * rB3);
            float psum = t1 + t2;
            outv[k] = sC + psum;      // = s_{t+1}
            sC = outv[k] + C4;
        }
        // batched store: one store instr per 8 steps; lane o stores step t+o
        float s01 = (o & 1) ? outv[1] : outv[0];
        float s23 = (o & 1) ? outv[3] : outv[2];
        float s45 = (o & 1) ? outv[5] : outv[4];
        float s67 = (o & 1) ? outv[7] : outv[6];
        float sA  = (o & 2) ? s23 : s01;
        float sB  = (o & 2) ? s67 : s45;
        float sv  = (o & 4) ? sB  : sA;
        __builtin_nontemporal_store(sv, op);
        op += (size_t)8 * B;
        // rotate x buffers, prefetch block t+16
        #pragma unroll
        for (int j = 0; j < 8; ++j) cur[j] = nxt[j];
        if (t + 16 < TT) {
            #pragma unroll
            for (int j = 0; j < 8; ++j)
                nxt[j] = __builtin_nontemporal_load(xp + (size_t)(t+16+j)*B);
        }
    }
}

extern "C" void kernel_launch(void* const* d_in, const int* in_sizes, int n_in,
                              void* d_out, int out_size, void* d_ws, size_t ws_size,
                              hipStream_t stream)
{
    const float* x  = (const float*)d_in[0];
    const float* W1 = (const float*)d_in[1];
    const float* A2 = (const float*)d_in[2];
    const float* A3 = (const float*)d_in[3];
    const float* W3 = (const float*)d_in[4];
    const float* W4 = (const float*)d_in[5];
    const float* W2 = (in_sizes[2] == 16) ? A2 : A3;
    const float* b2 = (in_sizes[2] == 16) ? A3 : A2;

    const int B = in_sizes[0] / TT;
    float* out = (float*)d_out;

    const int threads = B * 8;
    dim3 block(512);
    dim3 grid((threads + 511) / 512);
    hipLaunchKernelGGL(stn_nr_kernel, grid, block, 0, stream,
                       x, W1, W2, b2, W3, W4, out, B);
}

// Round 6
// 494.924 us; speedup vs baseline: 1.0666x; 1.0101x over previous
//
#include <hip/hip_runtime.h>

#define TT 2048

// Identity quad_perm DPP: value-preserving, but forces the result into a VGPR
// (prevents the compiler from keeping a wave-uniform weight in an SGPR, which
// would force v_mov fixups when two SGPR operands meet in one VALU op).
__device__ __forceinline__ float vlaunder(float v) {
    return __int_as_float(__builtin_amdgcn_mov_dpp(__float_as_int(v), 0xE4, 0xf, 0xf, true));
}

// r = 1/(1+2^z); tanh(y) = 1 - 2r with z = 2*log2(e)*y folded into weights.
// inf-safe: t=inf -> r=0, t=0 -> r=1.
__device__ __forceinline__ float sigr(float z) {
    return __builtin_amdgcn_rcpf(1.0f + __builtin_amdgcn_exp2f(z));
}

__global__ __launch_bounds__(64, 1)
void stn_ll_kernel(const float* __restrict__ x,
                   const float* __restrict__ W1,
                   const float* __restrict__ W2,
                   const float* __restrict__ b2,
                   const float* __restrict__ W3,
                   const float* __restrict__ W4,
                   float* __restrict__ out, int B)
{
    const int b = blockIdx.x * 64 + threadIdx.x;
    if (b >= B) return;
    const float K = 2.8853900817779268f; // 2*log2(e)

    // Folded weights: layers consume r directly. A' = -2K*W, B' = K*(bias+rowsum).
    // Layer4 fused into layer1 tail: Kf[i][j] = Ks_i * A4_j.
    float Kx[4], Ks[4], Bv2[4], Bv3[4], A2[4][4], A3[4][4], A4[4], Kf[4][4];
    float C4 = 0.f;
    #pragma unroll
    for (int j = 0; j < 4; ++j) { A4[j] = -2.f * W4[j]; C4 += W4[j]; }
    #pragma unroll
    for (int i = 0; i < 4; ++i) {
        Kx[i] = W1[2*i]   * K;
        Ks[i] = W1[2*i+1] * K;
        float s2 = b2[i], s3 = 0.f;
        #pragma unroll
        for (int j = 0; j < 4; ++j) {
            A2[i][j] = -2.f * K * W2[i*4+j];
            A3[i][j] = -2.f * K * W3[i*4+j];
            s2 += W2[i*4+j];
            s3 += W3[i*4+j];
            Kf[i][j] = Ks[i] * A4[j];
        }
        Bv2[i] = vlaunder(s2 * K);   // addends must be VGPR (they meet an
        Bv3[i] = vlaunder(s3 * K);   // SGPR coeff in the innermost fma)
    }

    const float* xp = x + b;
    float* op = out + b;

    // 16-step ping-pong x buffers, no rotation copies.
    float bufA[8], bufB[8];
    #pragma unroll
    for (int j = 0; j < 8; ++j) bufA[j] = __builtin_nontemporal_load(xp + j*B);
    #pragma unroll
    for (int j = 0; j < 8; ++j) bufB[j] = __builtin_nontemporal_load(xp + (8+j)*B);

    // Carried: z1[i] (layer-1 preactivation), sC = s_t + C4, s_0 = 0.
    float z1[4];
    #pragma unroll
    for (int i = 0; i < 4; ++i) z1[i] = Kx[i] * bufA[0];
    float sC = C4;

    for (int t = 0; t < TT; t += 16) {
        // ---------- half 1: steps t..t+7 from bufA ----------
        #pragma unroll
        for (int k = 0; k < 8; ++k) {
            float r1[4], r2[4], r3[4];
            #pragma unroll
            for (int i = 0; i < 4; ++i) r1[i] = sigr(z1[i]);
            // off-chain: pre_i for next step (needs x_{t+k+1} and current sC)
            float xn = (k < 7) ? bufA[k+1] : bufB[0];
            float pre[4];
            #pragma unroll
            for (int i = 0; i < 4; ++i) pre[i] = fmaf(Ks[i], sC, Kx[i] * xn);
            // layer 2: depth-3 trees
            #pragma unroll
            for (int i = 0; i < 4; ++i) {
                float f = fmaf(A2[i][1], r1[1], fmaf(A2[i][0], r1[0], Bv2[i]));
                float g = fmaf(A2[i][3], r1[3], A2[i][2] * r1[2]);
                r2[i] = sigr(f + g);
            }
            // layer 3
            #pragma unroll
            for (int i = 0; i < 4; ++i) {
                float f = fmaf(A3[i][1], r2[1], fmaf(A3[i][0], r2[0], Bv3[i]));
                float g = fmaf(A3[i][3], r2[3], A3[i][2] * r2[2]);
                r3[i] = sigr(f + g);
            }
            // tail: z1' = pre + sum_j Kf[i][j]*r3_j (depth-3, layer4 fused)
            #pragma unroll
            for (int i = 0; i < 4; ++i) {
                float f = fmaf(Kf[i][1], r3[1], fmaf(Kf[i][0], r3[0], pre[i]));
                float g = fmaf(Kf[i][3], r3[3], Kf[i][2] * r3[2]);
                z1[i] = f + g;
            }
            // off-chain: output + state
            float p0 = fmaf(A4[1], r3[1], A4[0] * r3[0]);
            float p1 = fmaf(A4[3], r3[3], A4[2] * r3[2]);
            float o  = sC + (p0 + p1);          // = s_{t+1}
            __builtin_nontemporal_store(o, op);
            op += B;
            sC = o + C4;
        }
        // refill bufA with steps t+16..t+23 (used next iteration half 1)
        if (t + 16 < TT) {
            #pragma unroll
            for (int j = 0; j < 8; ++j)
                bufA[j] = __builtin_nontemporal_load(xp + (size_t)(t+16+j)*B);
        }
        // ---------- half 2: steps t+8..t+15 from bufB ----------
        #pragma unroll
        for (int k = 0; k < 8; ++k) {
            float r1[4], r2[4], r3[4];
            #pragma unroll
            for (int i = 0; i < 4; ++i) r1[i] = sigr(z1[i]);
            float xn = (k < 7) ? bufB[k+1] : bufA[0];  // bufA = t+16 block (or stale at end, unused)
            float pre[4];
            #pragma unroll
            for (int i = 0; i < 4; ++i) pre[i] = fmaf(Ks[i], sC, Kx[i] * xn);
            #pragma unroll
            for (int i = 0; i < 4; ++i) {
                float f = fmaf(A2[i][1], r1[1], fmaf(A2[i][0], r1[0], Bv2[i]));
                float g = fmaf(A2[i][3], r1[3], A2[i][2] * r1[2]);
                r2[i] = sigr(f + g);
            }
            #pragma unroll
            for (int i = 0; i < 4; ++i) {
                float f = fmaf(A3[i][1], r2[1], fmaf(A3[i][0], r2[0], Bv3[i]));
                float g = fmaf(A3[i][3], r2[3], A3[i][2] * r2[2]);
                r3[i] = sigr(f + g);
            }
            #pragma unroll
            for (int i = 0; i < 4; ++i) {
                float f = fmaf(Kf[i][1], r3[1], fmaf(Kf[i][0], r3[0], pre[i]));
                float g = fmaf(Kf[i][3], r3[3], Kf[i][2] * r3[2]);
                z1[i] = f + g;
            }
            float p0 = fmaf(A4[1], r3[1], A4[0] * r3[0]);
            float p1 = fmaf(A4[3], r3[3], A4[2] * r3[2]);
            float o  = sC + (p0 + p1);
            __builtin_nontemporal_store(o, op);
            op += B;
            sC = o + C4;
        }
        // refill bufB with steps t+24..t+31 (used next iteration half 2)
        if (t + 24 < TT) {
            #pragma unroll
            for (int j = 0; j < 8; ++j)
                bufB[j] = __builtin_nontemporal_load(xp + (size_t)(t+24+j)*B);
        }
    }
}

extern "C" void kernel_launch(void* const* d_in, const int* in_sizes, int n_in,
                              void* d_out, int out_size, void* d_ws, size_t ws_size,
                              hipStream_t stream)
{
    const float* x  = (const float*)d_in[0];
    const float* W1 = (const float*)d_in[1];
    const float* A2 = (const float*)d_in[2];
    const float* A3 = (const float*)d_in[3];
    const float* W3 = (const float*)d_in[4];
    const float* W4 = (const float*)d_in[5];
    const float* W2 = (in_sizes[2] == 16) ? A2 : A3;
    const float* b2 = (in_sizes[2] == 16) ? A3 : A2;

    const int B = in_sizes[0] / TT;
    float* out = (float*)d_out;

    dim3 block(64);
    dim3 grid((B + 63) / 64);
    hipLaunchKernelGGL(stn_ll_kernel, grid, block, 0, stream,
                       x, W1, W2, b2, W3, W4, out, B);
}

// Round 8
// 390.940 us; speedup vs baseline: 1.3504x; 1.2660x over previous
//
#include <hip/hip_runtime.h>

#define TT 2048

// DPP quad_perm cross-lane move (VALU pipe)
template<int CTRL>
__device__ __forceinline__ float dpp_f(float x) {
    return __int_as_float(__builtin_amdgcn_mov_dpp(__float_as_int(x), CTRL, 0xf, 0xf, true));
}
#define QP_ROT1 0x39  // lane i <- lane (i+1)&3
#define QP_ROT2 0x4E  // lane i <- lane (i+2)&3
#define QP_ROT3 0x93  // lane i <- lane (i+3)&3

// r = 1/(1+exp2(z));  tanh(y) = 1 - 2r with z = 2*log2(e)*y (folded into weights)
__device__ __forceinline__ float sigma_r(float z) {
    return __builtin_amdgcn_rcpf(1.0f + __builtin_amdgcn_exp2f(z));
}

__global__ __launch_bounds__(512, 2)
void stn_oct_kernel(const float* __restrict__ x,
                    const float* __restrict__ W1,
                    const float* __restrict__ W2,
                    const float* __restrict__ b2,
                    const float* __restrict__ W3,
                    const float* __restrict__ W4,
                    float* __restrict__ out, int B)
{
    const int tid = blockIdx.x * blockDim.x + threadIdx.x;
    const int o   = tid & 7;   // octet lane: two quads duplicate work; o also = store row
    const int q   = o & 3;     // hidden-unit index
    const int b   = tid >> 3;  // sequence index
    if (b >= B) return;
    const float K = 2.8853900817779268f; // 2*log2(e)

    // Folded weights: every layer consumes r (=sigmoid) directly.
    // z_layer = B' + sum_j A'_j * r_j, A' = -2K*W, B' = K*(bias + sum_j W_j)
    const float Kw1x = W1[2*q]   * K;
    const float Kw1s = W1[2*q+1] * K;
    float B2 = b2[q], B3 = 0.f, C4 = 0.f;
    float a2[4], a3[4], a4[4];
    #pragma unroll
    for (int r = 0; r < 4; ++r) {
        const int j = (q + r) & 3;           // rotation-aligned gather
        a2[r] = -2.f * K * W2[q*4 + j];
        a3[r] = -2.f * K * W3[q*4 + j];
        a4[r] = -2.f * W4[j];
        B2 += W2[q*4 + r];
        B3 += W3[q*4 + r];
        C4 += W4[r];
    }
    B2 *= K; B3 *= K;

    const float* xp = x + b;
    float* op = out + b + (size_t)o * B;

    float cur[8], nxt[8];
    #pragma unroll
    for (int j = 0; j < 8; ++j) cur[j] = __builtin_nontemporal_load(xp + j*B);
    #pragma unroll
    for (int j = 0; j < 8; ++j) nxt[j] = __builtin_nontemporal_load(xp + (8+j)*B);

    // State: psum = sum_j A4_j*r3_j from previous step (0 initially),
    // sC = s_t + C4, pre2 = Kw1x*x_t + Kw1s*(s_{t-1}+C4) so that
    // z1(t) = pre2 + Kw1s*psum.  s_0 = 0.
    float psum = 0.f;
    float sC   = C4;
    float pre2 = Kw1x * cur[0];

    for (int t = 0; t < TT; t += 8) {
        float outv[8];
        #pragma unroll
        for (int k = 0; k < 8; ++k) {
            // ---- critical chain head: layer 1 ----
            float z1 = fmaf(Kw1s, psum, pre2);
            float r1 = sigma_r(z1);
            // off-chain: prepare pre2 for next step (uses OLD sC = s_t + C4)
            float xn = (k < 7) ? cur[k+1] : nxt[0];
            pre2 = fmaf(Kw1s, sC, Kw1x * xn);
            // ---- layer 2 ----
            float rA = dpp_f<QP_ROT1>(r1);
            float rB = dpp_f<QP_ROT2>(r1);
            float rC = dpp_f<QP_ROT3>(r1);
            float m0 = fmaf(a2[0], r1, B2);
            float u1 = fmaf(a2[1], rA, m0);
            float v  = a2[2] * rB;
            float u2 = fmaf(a2[3], rC, v);
            float r2 = sigma_r(u1 + u2);
            // ---- layer 3 ----
            rA = dpp_f<QP_ROT1>(r2);
            rB = dpp_f<QP_ROT2>(r2);
            rC = dpp_f<QP_ROT3>(r2);
            m0 = fmaf(a3[0], r2, B3);
            u1 = fmaf(a3[1], rA, m0);
            v  = a3[2] * rB;
            u2 = fmaf(a3[3], rC, v);
            float r3 = sigma_r(u1 + u2);
            // ---- layer 4 quad-reduce (3-dpp tree, all lanes get sum) ----
            rA = dpp_f<QP_ROT1>(r3);
            rB = dpp_f<QP_ROT2>(r3);
            rC = dpp_f<QP_ROT3>(r3);
            float p0 = a4[0] * r3;
            u1 = fmaf(a4[1], rA, p0);
            v  = a4[2] * rB;
            u2 = fmaf(a4[3], rC, v);
            psum = u1 + u2;
            // off-chain: state & output
            outv[k] = sC + psum;      // = s_{t+1} (stored value)
            sC = outv[k] + C4;
        }
        // full-wave batched store: lane o stores step t+o
        float s01 = (o & 1) ? outv[1] : outv[0];
        float s23 = (o & 1) ? outv[3] : outv[2];
        float s45 = (o & 1) ? outv[5] : outv[4];
        float s67 = (o & 1) ? outv[7] : outv[6];
        float sA  = (o & 2) ? s23 : s01;
        float sB  = (o & 2) ? s67 : s45;
        float sv  = (o & 4) ? sB  : sA;
        __builtin_nontemporal_store(sv, op);
        op += (size_t)8 * B;
        // rotate x buffers, prefetch block t+16
        #pragma unroll
        for (int j = 0; j < 8; ++j) cur[j] = nxt[j];
        if (t + 16 < TT) {
            #pragma unroll
            for (int j = 0; j < 8; ++j)
                nxt[j] = __builtin_nontemporal_load(xp + (size_t)(t+16+j)*B);
        }
    }
}

extern "C" void kernel_launch(void* const* d_in, const int* in_sizes, int n_in,
                              void* d_out, int out_size, void* d_ws, size_t ws_size,
                              hipStream_t stream)
{
    const float* x  = (const float*)d_in[0];
    const float* W1 = (const float*)d_in[1];
    const float* A2 = (const float*)d_in[2];
    const float* A3 = (const float*)d_in[3];
    const float* W3 = (const float*)d_in[4];
    const float* W4 = (const float*)d_in[5];
    const float* W2 = (in_sizes[2] == 16) ? A2 : A3;
    const float* b2 = (in_sizes[2] == 16) ? A3 : A2;

    const int B = in_sizes[0] / TT;
    float* out = (float*)d_out;

    const int threads = B * 8;
    dim3 block(512);
    dim3 grid((threads + 511) / 512);
    hipLaunchKernelGGL(stn_oct_kernel, grid, block, 0, stream,
                       x, W1, W2, b2, W3, W4, out, B);
}